// Round 18
// baseline (408.928 us; speedup 1.0000x reference)
//
#include <hip/hip_runtime.h>

#define BB 8
#define TT 4096
#define DD 768
#define MM (BB*TT)   // 32768

typedef _Float16 f16;
typedef _Float16 f16x8 __attribute__((ext_vector_type(8)));
typedef float f32x4 __attribute__((ext_vector_type(4)));

typedef __attribute__((address_space(1))) void void_g;
typedef __attribute__((address_space(3))) void void_l;

// async global->LDS, 16B per lane. LDS dest = wave-uniform base + lane*16 (linear).
__device__ __forceinline__ void gload16(const void* g, void* l) {
  __builtin_amdgcn_global_load_lds((void_g*)g, (void_l*)l, 16, 0, 0);
}

// ---------------- f32 -> f16 convert (for weight matrices) ----------------
__global__ void cvt_f32_f16(const float* __restrict__ in, f16* __restrict__ out, int n) {
  int i0 = (blockIdx.x * blockDim.x + threadIdx.x) * 8;
  int stride = gridDim.x * blockDim.x * 8;
  for (int i = i0; i < n; i += stride) {
    float4 a = *(const float4*)(in + i);
    float4 b = *(const float4*)(in + i + 4);
    f16x8 o;
    o[0] = (f16)a.x; o[1] = (f16)a.y; o[2] = (f16)a.z; o[3] = (f16)a.w;
    o[4] = (f16)b.x; o[5] = (f16)b.y; o[6] = (f16)b.z; o[7] = (f16)b.w;
    *(f16x8*)(out + i) = o;
  }
}

// ---------------- proj Q: C = A*W^T + bias, DOUBLE-BUFFERED ----------------
// Tile 64m x 256n (grid 512 x 3), 4 waves (1m x 4n). Stage k+1 while
// computing k; ONE barrier/iter (attn11 pattern). LDS 40KB, 3 blocks/CU.
// C in dc-major fragment layout:
// idx = (((row>>6)*24 + (col>>5))*4 + ((row>>4)&3))*512
//       + ((row&15) + ((col>>3)&3)*16)*8 + (col&7)
// If Xout && n0==0, also write the cvt'd A-tile (f16 X, row-major).
__global__ __launch_bounds__(256, 3)
void proj_gemmQ(const float* __restrict__ Af, const f16* __restrict__ Wh,
                const float* __restrict__ bias, f16* __restrict__ C,
                f16* __restrict__ Xout) {
  __shared__ f16 As[2][64 * 32];
  __shared__ f16 Ws[2][256 * 32];
  const int m0 = blockIdx.x * 64;
  const int n0 = blockIdx.y * 256;
  const int t = threadIdx.x;
  const int lane = t & 63;
  const int w = t >> 6;
  const int wn = w * 64;
  const int fr = lane & 15, fq = lane >> 4;
  const int xst = ((t >> 3) & 3) << 3;
  const int xrd = ((fr >> 1) & 3) << 3;

  f32x4 acc[4][4] = {};

  const int r0 = t >> 2, cA = (t & 3) * 8;
  const int e0 = t * 8;
  const int c8 = ((t & 3) ^ ((t >> 3) & 3)) * 8;
  const f16* w0 = Wh + (size_t)(n0 + r0) * DD + c8;
  const bool wout = (Xout != nullptr) && (n0 == 0);

#define PSTAGE(bf, ks_) do { \
    const int k0_ = (ks_) * 32; \
    gload16(w0 + k0_,                      &Ws[bf][w * 512]); \
    gload16(w0 + (size_t)64  * DD + k0_,   &Ws[bf][2048 + w * 512]); \
    gload16(w0 + (size_t)128 * DD + k0_,   &Ws[bf][4096 + w * 512]); \
    gload16(w0 + (size_t)192 * DD + k0_,   &Ws[bf][6144 + w * 512]); \
    { \
      const float* g0 = Af + (size_t)(m0 + r0) * DD + k0_ + cA; \
      float4 x0 = *(const float4*)g0, x1 = *(const float4*)(g0 + 4); \
      f16x8 va; \
      va[0] = (f16)x0.x; va[1] = (f16)x0.y; va[2] = (f16)x0.z; va[3] = (f16)x0.w; \
      va[4] = (f16)x1.x; va[5] = (f16)x1.y; va[6] = (f16)x1.z; va[7] = (f16)x1.w; \
      *(f16x8*)&As[bf][e0 ^ xst] = va; \
      if (wout) *(f16x8*)&Xout[(size_t)(m0 + r0) * DD + k0_ + cA] = va; \
    } \
  } while (0)

  PSTAGE(0, 0);
  __syncthreads();

  for (int ks = 0; ks < 24; ++ks) {
    const int bf = ks & 1;
    if (ks + 1 < 24) PSTAGE(bf ^ 1, ks + 1);
    f16x8 a[4], b[4];
#pragma unroll
    for (int i = 0; i < 4; ++i)
      a[i] = *(const f16x8*)&As[bf][(((i * 16 + fr) * 32) + fq * 8) ^ xrd];
#pragma unroll
    for (int j = 0; j < 4; ++j)
      b[j] = *(const f16x8*)&Ws[bf][(((wn + j * 16 + fr) * 32) + fq * 8) ^ xrd];
#pragma unroll
    for (int i = 0; i < 4; ++i)
#pragma unroll
      for (int j = 0; j < 4; ++j)
        acc[i][j] = __builtin_amdgcn_mfma_f32_16x16x32_f16(a[i], b[j], acc[i][j], 0, 0, 0);
    __syncthreads();
  }
#undef PSTAGE

#pragma unroll
  for (int j = 0; j < 4; ++j) {
    const int col = n0 + wn + j * 16 + fr;
    const float bv = bias[col];
#pragma unroll
    for (int i = 0; i < 4; ++i) {
#pragma unroll
      for (int r = 0; r < 4; ++r) {
        const int row = m0 + i * 16 + fq * 4 + r;
        const f16 v = (f16)(acc[i][j][r] + bv);
        const size_t idx = (((size_t)(row >> 6) * 24 + (col >> 5)) * 4 +
                            ((row >> 4) & 3)) * 512 +
                           ((row & 15) + (((col >> 3) & 3) << 4)) * 8 + (col & 7);
        C[idx] = v;
      }
    }
  }
}

// ---------------- proj K: all-gload16 from Xh (f16), DOUBLE-BUFFERED ------
__global__ __launch_bounds__(256, 3)
void proj_gemmK(const f16* __restrict__ Xh, const f16* __restrict__ Wh,
                const float* __restrict__ bias, f16* __restrict__ C) {
  __shared__ f16 As[2][64 * 32];
  __shared__ f16 Ws[2][256 * 32];
  const int m0 = blockIdx.x * 64;
  const int n0 = blockIdx.y * 256;
  const int t = threadIdx.x;
  const int lane = t & 63;
  const int w = t >> 6;
  const int wn = w * 64;
  const int fr = lane & 15, fq = lane >> 4;
  const int xrd = ((fr >> 1) & 3) << 3;

  f32x4 acc[4][4] = {};

  const int r0 = t >> 2;
  const int c8 = ((t & 3) ^ ((t >> 3) & 3)) * 8;
  const f16* w0 = Wh + (size_t)(n0 + r0) * DD + c8;
  const f16* x0 = Xh + (size_t)(m0 + r0) * DD + c8;

#define PSTAGE(bf, ks_) do { \
    const int k0_ = (ks_) * 32; \
    gload16(x0 + k0_,                      &As[bf][w * 512]); \
    gload16(w0 + k0_,                      &Ws[bf][w * 512]); \
    gload16(w0 + (size_t)64  * DD + k0_,   &Ws[bf][2048 + w * 512]); \
    gload16(w0 + (size_t)128 * DD + k0_,   &Ws[bf][4096 + w * 512]); \
    gload16(w0 + (size_t)192 * DD + k0_,   &Ws[bf][6144 + w * 512]); \
  } while (0)

  PSTAGE(0, 0);
  __syncthreads();

  for (int ks = 0; ks < 24; ++ks) {
    const int bf = ks & 1;
    if (ks + 1 < 24) PSTAGE(bf ^ 1, ks + 1);
    f16x8 a[4], b[4];
#pragma unroll
    for (int i = 0; i < 4; ++i)
      a[i] = *(const f16x8*)&As[bf][(((i * 16 + fr) * 32) + fq * 8) ^ xrd];
#pragma unroll
    for (int j = 0; j < 4; ++j)
      b[j] = *(const f16x8*)&Ws[bf][(((wn + j * 16 + fr) * 32) + fq * 8) ^ xrd];
#pragma unroll
    for (int i = 0; i < 4; ++i)
#pragma unroll
      for (int j = 0; j < 4; ++j)
        acc[i][j] = __builtin_amdgcn_mfma_f32_16x16x32_f16(a[i], b[j], acc[i][j], 0, 0, 0);
    __syncthreads();
  }
#undef PSTAGE

#pragma unroll
  for (int j = 0; j < 4; ++j) {
    const int col = n0 + wn + j * 16 + fr;
    const float bv = bias[col];
#pragma unroll
    for (int i = 0; i < 4; ++i) {
#pragma unroll
      for (int r = 0; r < 4; ++r) {
        const int row = m0 + i * 16 + fq * 4 + r;
        C[(size_t)row * DD + col] = (f16)(acc[i][j][r] + bv);
      }
    }
  }
}

// ---------------- proj fallback (K from f32 X, reg-cvt), DOUBLE-BUFFERED --
__global__ __launch_bounds__(256, 3)
void proj_gemm3(const float* __restrict__ Af, const f16* __restrict__ Wh,
                const float* __restrict__ bias, f16* __restrict__ C) {
  __shared__ f16 As[2][64 * 32];
  __shared__ f16 Ws[2][256 * 32];
  const int m0 = blockIdx.x * 64;
  const int n0 = blockIdx.y * 256;
  const int t = threadIdx.x;
  const int lane = t & 63;
  const int w = t >> 6;
  const int wn = w * 64;
  const int fr = lane & 15, fq = lane >> 4;
  const int xst = ((t >> 3) & 3) << 3;
  const int xrd = ((fr >> 1) & 3) << 3;
  f32x4 acc[4][4] = {};
  const int r0 = t >> 2, cA = (t & 3) * 8;
  const int e0 = t * 8;
  const int c8 = ((t & 3) ^ ((t >> 3) & 3)) * 8;
  const f16* w0 = Wh + (size_t)(n0 + r0) * DD + c8;

#define PSTAGE(bf, ks_) do { \
    const int k0_ = (ks_) * 32; \
    gload16(w0 + k0_,                      &Ws[bf][w * 512]); \
    gload16(w0 + (size_t)64  * DD + k0_,   &Ws[bf][2048 + w * 512]); \
    gload16(w0 + (size_t)128 * DD + k0_,   &Ws[bf][4096 + w * 512]); \
    gload16(w0 + (size_t)192 * DD + k0_,   &Ws[bf][6144 + w * 512]); \
    { \
      const float* g0 = Af + (size_t)(m0 + r0) * DD + k0_ + cA; \
      float4 x0 = *(const float4*)g0, x1 = *(const float4*)(g0 + 4); \
      f16x8 va; \
      va[0] = (f16)x0.x; va[1] = (f16)x0.y; va[2] = (f16)x0.z; va[3] = (f16)x0.w; \
      va[4] = (f16)x1.x; va[5] = (f16)x1.y; va[6] = (f16)x1.z; va[7] = (f16)x1.w; \
      *(f16x8*)&As[bf][e0 ^ xst] = va; \
    } \
  } while (0)

  PSTAGE(0, 0);
  __syncthreads();

  for (int ks = 0; ks < 24; ++ks) {
    const int bf = ks & 1;
    if (ks + 1 < 24) PSTAGE(bf ^ 1, ks + 1);
    f16x8 a[4], b[4];
#pragma unroll
    for (int i = 0; i < 4; ++i)
      a[i] = *(const f16x8*)&As[bf][(((i * 16 + fr) * 32) + fq * 8) ^ xrd];
#pragma unroll
    for (int j = 0; j < 4; ++j)
      b[j] = *(const f16x8*)&Ws[bf][(((wn + j * 16 + fr) * 32) + fq * 8) ^ xrd];
#pragma unroll
    for (int i = 0; i < 4; ++i)
#pragma unroll
      for (int j = 0; j < 4; ++j)
        acc[i][j] = __builtin_amdgcn_mfma_f32_16x16x32_f16(a[i], b[j], acc[i][j], 0, 0, 0);
    __syncthreads();
  }
#undef PSTAGE

#pragma unroll
  for (int j = 0; j < 4; ++j) {
    const int col = n0 + wn + j * 16 + fr;
    const float bv = bias[col];
#pragma unroll
    for (int i = 0; i < 4; ++i)
#pragma unroll
      for (int r = 0; r < 4; ++r) {
        const int row = m0 + i * 16 + fq * 4 + r;
        C[(size_t)row * DD + col] = (f16)(acc[i][j][r] + bv);
      }
  }
}

// ---------------- attn15: attn14 + s_setprio around MFMA (T5) -------------
// Structure identical to attn14 (K-step-64 phases, one-sub-ahead Q prefetch,
// dbuf 32KB LDS, no-max Z). setprio(1) wraps each 16-MFMA cluster: with 3
// independent blocks/CU at drifted phases, scheduler prefers MFMA-ready
// waves over sibling staging waves. (256,3); regs unchanged (~145 w/ AGPR).
__global__ __launch_bounds__(256, 3)
void attn15(const f16* __restrict__ Qf, const f16* __restrict__ K,
            const int* __restrict__ mask, float* __restrict__ pzv,
            float* __restrict__ sdg) {
  __shared__ f16 Ks[2][128 * 64];

  const int bid = blockIdx.x;
  const int qs = bid / 24;
  const int kh = (bid % 24) >> 3;
  const int bb = bid & 7;
  const int t = threadIdx.x, l = t & 63, w = t >> 6;
  const int wq = w >> 1, wk = w & 1;
  const int fr = l & 15, fq = l >> 4;
  const int q0 = qs * 128;
  const float scale = 0.036084391824351613f;  // 1/sqrt(768)
  const int lo = kh * 11;
  const int cnt = (kh < 2) ? 11 : 10;
  const int P = cnt * 12;

  const f16* Kg = K + (size_t)bb * TT * DD;

  const int grp = bb * 64 + qs * 2 + wq;
  const f16* qf = Qf + (size_t)grp * 24 * 4 * 512 + (size_t)l * 8;

  const int c8 = ((t & 3) ^ ((t >> 3) & 3)) * 8;
  const f16* klo = Kg + (size_t)(t >> 2) * DD + c8;
  const f16* khi = klo + (size_t)64 * DD;

  const int sx = (fq ^ ((fr >> 1) & 3)) * 8;
  const int bbase = (wk * 64 + fr) * 32 + sx;

  f32x4 acc[4][4] = {};
  f32x4 zacc[4] = {};
  int im0 = 1, im1 = 1, im2 = 1, im3 = 1;
  f16x8 avA[4], avB[4];

#define STAGE(bf, p_) do { \
    const size_t o0 = (size_t)(lo + (p_) / 12) * 128 * DD + (size_t)(((p_) % 12) * 64); \
    gload16(klo + o0,      &Ks[bf][w * 512]); \
    gload16(khi + o0,      &Ks[bf][2048 + w * 512]); \
    gload16(klo + o0 + 32, &Ks[bf][4096 + w * 512]); \
    gload16(khi + o0 + 32, &Ks[bf][6144 + w * 512]); \
  } while (0)

#define QLOAD(dst, dc_) do { \
    const f16* qp_ = qf + (size_t)(dc_) * 2048; \
    _Pragma("unroll") \
    for (int i = 0; i < 4; ++i) (dst)[i] = *(const f16x8*)(qp_ + i * 512); \
  } while (0)

#define MFMA_ALL(av_, bufv, off_) do { \
    f16x8 bv[4]; \
    _Pragma("unroll") \
    for (int j = 0; j < 4; ++j) bv[j] = *(const f16x8*)&Ks[bufv][(off_) + bbase + j * 512]; \
    __builtin_amdgcn_s_setprio(1); \
    _Pragma("unroll") \
    for (int i = 0; i < 4; ++i) \
      _Pragma("unroll") \
      for (int j = 0; j < 4; ++j) \
        acc[i][j] = __builtin_amdgcn_mfma_f32_16x16x32_f16((av_)[i], bv[j], acc[i][j], 0, 0, 0); \
    __builtin_amdgcn_s_setprio(0); \
  } while (0)

#define KT_EPILOGUE(kt_) do { \
    const float mb0 = im0 ? 0.f : -1e30f; \
    const float mb1 = im1 ? 0.f : -1e30f; \
    const float mb2 = im2 ? 0.f : -1e30f; \
    const float mb3 = im3 ? 0.f : -1e30f; \
    const bool isdiag = ((kt_) == qs); \
    _Pragma("unroll") \
    for (int i = 0; i < 4; ++i) { \
      _Pragma("unroll") \
      for (int rg = 0; rg < 4; ++rg) { \
        float v0 = fmaf(acc[i][0][rg], scale, mb0); \
        float v1 = fmaf(acc[i][1][rg], scale, mb1); \
        float v2 = fmaf(acc[i][2][rg], scale, mb2); \
        float v3 = fmaf(acc[i][3][rg], scale, mb3); \
        if (isdiag) { \
          const int rl = wq * 64 + i * 16 + fq * 4 + rg; \
          const int cl = wk * 64 + fr; \
          if (cl      == rl) sdg[(size_t)bb * TT + q0 + rl] = v0; \
          if (cl + 16 == rl) sdg[(size_t)bb * TT + q0 + rl] = v1; \
          if (cl + 32 == rl) sdg[(size_t)bb * TT + q0 + rl] = v2; \
          if (cl + 48 == rl) sdg[(size_t)bb * TT + q0 + rl] = v3; \
        } \
        zacc[i][rg] += __expf(v0) + __expf(v1) + __expf(v2) + __expf(v3); \
      } \
    } \
    _Pragma("unroll") \
    for (int i = 0; i < 4; ++i) \
      _Pragma("unroll") \
      for (int j = 0; j < 4; ++j) acc[i][j] = (f32x4)(0.f); \
  } while (0)

  // prologue: stage phase 0; prefetch avA (dc=0)
  STAGE(0, 0);
  QLOAD(avA, 0);
  __syncthreads();

  for (int p = 0; p < P; ++p) {
    const int buf = p & 1;
    const int kt = lo + p / 12, c = p % 12;   // phase covers dcs 2c, 2c+1
    if (c == 0) {  // preload mask for this kt (consumed at c==11)
      const int kb = bb * TT + kt * 128 + wk * 64 + fr;
      im0 = mask[kb]; im1 = mask[kb + 16]; im2 = mask[kb + 32]; im3 = mask[kb + 48];
    }

    // ---- sub A: prefetch avB(dc 2c+1), stage next phase; MFMA(avA, cols 0-31)
    QLOAD(avB, 2 * c + 1);
    if (p + 1 < P) STAGE(buf ^ 1, p + 1);
    MFMA_ALL(avA, buf, 0);

    // ---- sub B: prefetch avA(next phase dc), MFMA(avB, cols 32-63)
    if (p + 1 < P) QLOAD(avA, 2 * (((p + 1) % 12)));
    MFMA_ALL(avB, buf, 4096);

    if (c == 11) KT_EPILOGUE(kt);

    __syncthreads();
  }
#undef STAGE
#undef QLOAD
#undef MFMA_ALL
#undef KT_EPILOGUE

  // reduce zacc across the 16 fr-lanes; write per-(kh,wk) partial Z (6 slots)
  const int slot = kh * 2 + wk;
#pragma unroll
  for (int i = 0; i < 4; ++i) {
#pragma unroll
    for (int rg = 0; rg < 4; ++rg) {
      float z = zacc[i][rg];
#pragma unroll
      for (int off = 1; off < 16; off <<= 1) z += __shfl_xor(z, off);
      if (fr == 0) {
        const int row = wq * 64 + i * 16 + fq * 4 + rg;
        pzv[(size_t)slot * MM + bb * TT + q0 + row] = z;
      }
    }
  }
}

// ---------------- merge 6 partials -> wdiag (+ zero out) ----------------
__global__ void merge6(const float* __restrict__ pz, const float* __restrict__ sdg,
                       float* __restrict__ wdiag, float* __restrict__ out) {
  int i = blockIdx.x * 256 + threadIdx.x;
  if (i < BB * DD) out[i] = 0.f;
  if (i >= MM) return;
  float Z = 0.f;
#pragma unroll
  for (int s = 0; s < 6; ++s) Z += pz[(size_t)s * MM + i];
  wdiag[i] = __expf(sdg[i]) / Z;
}

// out[b,d] = sum_t X[b,t,d] * wdiag[b,t]  (f32 X fallback)
__global__ __launch_bounds__(256)
void out_gemv(const float* __restrict__ X, const float* __restrict__ wdiag,
              float* __restrict__ out) {
  __shared__ float wsm[256];
  const int b = blockIdx.z;
  const int d = blockIdx.y * 256 + threadIdx.x;
  const int tbase = blockIdx.x * 256;
  wsm[threadIdx.x] = wdiag[b * TT + tbase + threadIdx.x];
  __syncthreads();
  float acc = 0.f;
  const float* xp = X + (size_t)(b * TT + tbase) * DD + d;
#pragma unroll 4
  for (int i = 0; i < 256; ++i) acc += xp[(size_t)i * DD] * wsm[i];
  atomicAdd(&out[b * DD + d], acc);
}

// out[b,d] = sum_t Xh[b,t,d] * wdiag[b,t]  (f16 X, half the traffic)
__global__ __launch_bounds__(256)
void out_gemv_h(const f16* __restrict__ Xh, const float* __restrict__ wdiag,
                float* __restrict__ out) {
  __shared__ float wsm[256];
  const int b = blockIdx.z;
  const int d = blockIdx.y * 256 + threadIdx.x;
  const int tbase = blockIdx.x * 256;
  wsm[threadIdx.x] = wdiag[b * TT + tbase + threadIdx.x];
  __syncthreads();
  float acc = 0.f;
  const f16* xp = Xh + (size_t)(b * TT + tbase) * DD + d;
#pragma unroll 4
  for (int i = 0; i < 256; ++i) acc += (float)xp[(size_t)i * DD] * wsm[i];
  atomicAdd(&out[b * DD + d], acc);
}

extern "C" void kernel_launch(void* const* d_in, const int* in_sizes, int n_in,
                              void* d_out, int out_size, void* d_ws, size_t ws_size,
                              hipStream_t stream) {
  const float* X    = (const float*)d_in[0];
  const int*   mask = (const int*)d_in[1];
  const float* Wq_w = (const float*)d_in[2];
  const float* Wq_b = (const float*)d_in[3];
  const float* Wk_w = (const float*)d_in[4];
  const float* Wk_b = (const float*)d_in[5];
  float* out = (float*)d_out;

  const size_t n2 = (size_t)MM * DD;              // 25.17M f16 elems
  const size_t wreg = 2 * (size_t)DD * DD;        // 2 weight mats (f16 elems)
  const size_t need_full = (3 * n2 + wreg) * sizeof(f16);  // ~153.4 MB
  const bool useXh = ws_size >= need_full;

  f16* Qf  = (f16*)d_ws;                          // fragment-major Q
  f16* Kh  = Qf + n2;                             // row-major K
  f16* Xh  = useXh ? (Kh + n2) : nullptr;         // f16 copy of X
  f16* Wqh = useXh ? (Xh + n2) : (Kh + n2);       // f16 weights (dead after proj)
  f16* Wkh = Wqh + (size_t)DD * DD;
  float* pz    = (float*)Wqh;                     // alias after proj reads
  float* sdg   = pz + 6 * (size_t)MM;
  float* wdiag = sdg + MM;

  cvt_f32_f16<<<288, 256, 0, stream>>>(Wq_w, Wqh, DD * DD);
  cvt_f32_f16<<<288, 256, 0, stream>>>(Wk_w, Wkh, DD * DD);

  proj_gemmQ<<<dim3(512, 3), 256, 0, stream>>>(X, Wqh, Wq_b, Qf, Xh);
  if (useXh)
    proj_gemmK<<<dim3(512, 3), 256, 0, stream>>>(Xh, Wkh, Wk_b, Kh);
  else
    proj_gemm3<<<dim3(512, 3), 256, 0, stream>>>(X, Wkh, Wk_b, Kh);

  attn15<<<768, 256, 0, stream>>>(Qf, Kh, mask, pz, sdg);

  merge6<<<128, 256, 0, stream>>>(pz, sdg, wdiag, out);

  if (useXh)
    out_gemv_h<<<dim3(16, 3, 8), 256, 0, stream>>>(Xh, wdiag, out);
  else
    out_gemv<<<dim3(16, 3, 8), 256, 0, stream>>>(X, wdiag, out);
}

// Round 19
// 403.638 us; speedup vs baseline: 1.0131x; 1.0131x over previous
//
#include <hip/hip_runtime.h>

#define BB 8
#define TT 4096
#define DD 768
#define MM (BB*TT)   // 32768

typedef _Float16 f16;
typedef _Float16 f16x8 __attribute__((ext_vector_type(8)));
typedef float f32x4 __attribute__((ext_vector_type(4)));

typedef __attribute__((address_space(1))) void void_g;
typedef __attribute__((address_space(3))) void void_l;

// async global->LDS, 16B per lane. LDS dest = wave-uniform base + lane*16 (linear).
__device__ __forceinline__ void gload16(const void* g, void* l) {
  __builtin_amdgcn_global_load_lds((void_g*)g, (void_l*)l, 16, 0, 0);
}

// ---------------- both weight matrices f32 -> f16, one launch -------------
__global__ void cvt2_f32_f16(const float* __restrict__ a, const float* __restrict__ b,
                             f16* __restrict__ oa, f16* __restrict__ ob, int n) {
  int i = (blockIdx.x * blockDim.x + threadIdx.x) * 8;
  if (i >= 2 * n) return;
  const float* src = (i < n) ? a : b;
  f16* dst = (i < n) ? oa : ob;
  const int j = (i < n) ? i : i - n;
  float4 x = *(const float4*)(src + j);
  float4 y = *(const float4*)(src + j + 4);
  f16x8 o;
  o[0] = (f16)x.x; o[1] = (f16)x.y; o[2] = (f16)x.z; o[3] = (f16)x.w;
  o[4] = (f16)y.x; o[5] = (f16)y.y; o[6] = (f16)y.z; o[7] = (f16)y.w;
  *(f16x8*)(dst + j) = o;
}

// ---------------- fused proj dispatch: z=0 -> Q (frag layout), z=1 -> K ----
// Tile 64m x 256n (grid 512 x 3 x 2), 4 waves (1m x 4n), double-buffered
// (stage k+1 while computing k, ONE barrier/iter). LDS 40KB, 3 blocks/CU.
// Both paths read f32 X (reg-cvt staging) -> Q and K dispatch-independent,
// co-resident; tails overlap. Q path also writes Xh (f16 X) when n0==0.
// Qf fragment layout:
// idx = (((row>>6)*24 + (col>>5))*4 + ((row>>4)&3))*512
//       + ((row&15) + ((col>>3)&3)*16)*8 + (col&7)
__global__ __launch_bounds__(256, 3)
void proj_qk(const float* __restrict__ Af,
             const f16* __restrict__ Wqh, const f16* __restrict__ Wkh,
             const float* __restrict__ bq, const float* __restrict__ bk,
             f16* __restrict__ Qf, f16* __restrict__ Kh,
             f16* __restrict__ Xout) {
  __shared__ f16 As[2][64 * 32];
  __shared__ f16 Ws[2][256 * 32];
  const int isK = blockIdx.z;
  const f16* Wh = isK ? Wkh : Wqh;
  const float* bias = isK ? bk : bq;
  const int m0 = blockIdx.x * 64;
  const int n0 = blockIdx.y * 256;
  const int t = threadIdx.x;
  const int lane = t & 63;
  const int w = t >> 6;
  const int wn = w * 64;
  const int fr = lane & 15, fq = lane >> 4;
  const int xst = ((t >> 3) & 3) << 3;
  const int xrd = ((fr >> 1) & 3) << 3;

  f32x4 acc[4][4] = {};

  const int r0 = t >> 2, cA = (t & 3) * 8;
  const int e0 = t * 8;
  const int c8 = ((t & 3) ^ ((t >> 3) & 3)) * 8;
  const f16* w0 = Wh + (size_t)(n0 + r0) * DD + c8;
  const bool wout = (Xout != nullptr) && (!isK) && (n0 == 0);

#define PSTAGE(bf, ks_) do { \
    const int k0_ = (ks_) * 32; \
    gload16(w0 + k0_,                      &Ws[bf][w * 512]); \
    gload16(w0 + (size_t)64  * DD + k0_,   &Ws[bf][2048 + w * 512]); \
    gload16(w0 + (size_t)128 * DD + k0_,   &Ws[bf][4096 + w * 512]); \
    gload16(w0 + (size_t)192 * DD + k0_,   &Ws[bf][6144 + w * 512]); \
    { \
      const float* g0 = Af + (size_t)(m0 + r0) * DD + k0_ + cA; \
      float4 x0 = *(const float4*)g0, x1 = *(const float4*)(g0 + 4); \
      f16x8 va; \
      va[0] = (f16)x0.x; va[1] = (f16)x0.y; va[2] = (f16)x0.z; va[3] = (f16)x0.w; \
      va[4] = (f16)x1.x; va[5] = (f16)x1.y; va[6] = (f16)x1.z; va[7] = (f16)x1.w; \
      *(f16x8*)&As[bf][e0 ^ xst] = va; \
      if (wout) *(f16x8*)&Xout[(size_t)(m0 + r0) * DD + k0_ + cA] = va; \
    } \
  } while (0)

  PSTAGE(0, 0);
  __syncthreads();

  for (int ks = 0; ks < 24; ++ks) {
    const int bf = ks & 1;
    if (ks + 1 < 24) PSTAGE(bf ^ 1, ks + 1);
    f16x8 a[4], b[4];
#pragma unroll
    for (int i = 0; i < 4; ++i)
      a[i] = *(const f16x8*)&As[bf][(((i * 16 + fr) * 32) + fq * 8) ^ xrd];
#pragma unroll
    for (int j = 0; j < 4; ++j)
      b[j] = *(const f16x8*)&Ws[bf][(((wn + j * 16 + fr) * 32) + fq * 8) ^ xrd];
#pragma unroll
    for (int i = 0; i < 4; ++i)
#pragma unroll
      for (int j = 0; j < 4; ++j)
        acc[i][j] = __builtin_amdgcn_mfma_f32_16x16x32_f16(a[i], b[j], acc[i][j], 0, 0, 0);
    __syncthreads();
  }
#undef PSTAGE

#pragma unroll
  for (int j = 0; j < 4; ++j) {
    const int col = n0 + wn + j * 16 + fr;
    const float bv = bias[col];
#pragma unroll
    for (int i = 0; i < 4; ++i) {
#pragma unroll
      for (int r = 0; r < 4; ++r) {
        const int row = m0 + i * 16 + fq * 4 + r;
        const f16 v = (f16)(acc[i][j][r] + bv);
        if (!isK) {
          const size_t idx = (((size_t)(row >> 6) * 24 + (col >> 5)) * 4 +
                              ((row >> 4) & 3)) * 512 +
                             ((row & 15) + (((col >> 3) & 3) << 4)) * 8 + (col & 7);
          Qf[idx] = v;
        } else {
          Kh[(size_t)row * DD + col] = v;
        }
      }
    }
  }
}

// ---------------- attn15: structural-floor kernel (unchanged) -------------
// K-step-64 phases, one-sub-ahead Q prefetch, dbuf 32KB LDS, no-max Z,
// setprio around MFMA. (256,3). Grid 768: bid = qs*24 + kh*8 + bb.
__global__ __launch_bounds__(256, 3)
void attn15(const f16* __restrict__ Qf, const f16* __restrict__ K,
            const int* __restrict__ mask, float* __restrict__ pzv,
            float* __restrict__ sdg) {
  __shared__ f16 Ks[2][128 * 64];

  const int bid = blockIdx.x;
  const int qs = bid / 24;
  const int kh = (bid % 24) >> 3;
  const int bb = bid & 7;
  const int t = threadIdx.x, l = t & 63, w = t >> 6;
  const int wq = w >> 1, wk = w & 1;
  const int fr = l & 15, fq = l >> 4;
  const int q0 = qs * 128;
  const float scale = 0.036084391824351613f;  // 1/sqrt(768)
  const int lo = kh * 11;
  const int cnt = (kh < 2) ? 11 : 10;
  const int P = cnt * 12;

  const f16* Kg = K + (size_t)bb * TT * DD;

  const int grp = bb * 64 + qs * 2 + wq;
  const f16* qf = Qf + (size_t)grp * 24 * 4 * 512 + (size_t)l * 8;

  const int c8 = ((t & 3) ^ ((t >> 3) & 3)) * 8;
  const f16* klo = Kg + (size_t)(t >> 2) * DD + c8;
  const f16* khi = klo + (size_t)64 * DD;

  const int sx = (fq ^ ((fr >> 1) & 3)) * 8;
  const int bbase = (wk * 64 + fr) * 32 + sx;

  f32x4 acc[4][4] = {};
  f32x4 zacc[4] = {};
  int im0 = 1, im1 = 1, im2 = 1, im3 = 1;
  f16x8 avA[4], avB[4];

#define STAGE(bf, p_) do { \
    const size_t o0 = (size_t)(lo + (p_) / 12) * 128 * DD + (size_t)(((p_) % 12) * 64); \
    gload16(klo + o0,      &Ks[bf][w * 512]); \
    gload16(khi + o0,      &Ks[bf][2048 + w * 512]); \
    gload16(klo + o0 + 32, &Ks[bf][4096 + w * 512]); \
    gload16(khi + o0 + 32, &Ks[bf][6144 + w * 512]); \
  } while (0)

#define QLOAD(dst, dc_) do { \
    const f16* qp_ = qf + (size_t)(dc_) * 2048; \
    _Pragma("unroll") \
    for (int i = 0; i < 4; ++i) (dst)[i] = *(const f16x8*)(qp_ + i * 512); \
  } while (0)

#define MFMA_ALL(av_, bufv, off_) do { \
    f16x8 bv[4]; \
    _Pragma("unroll") \
    for (int j = 0; j < 4; ++j) bv[j] = *(const f16x8*)&Ks[bufv][(off_) + bbase + j * 512]; \
    __builtin_amdgcn_s_setprio(1); \
    _Pragma("unroll") \
    for (int i = 0; i < 4; ++i) \
      _Pragma("unroll") \
      for (int j = 0; j < 4; ++j) \
        acc[i][j] = __builtin_amdgcn_mfma_f32_16x16x32_f16((av_)[i], bv[j], acc[i][j], 0, 0, 0); \
    __builtin_amdgcn_s_setprio(0); \
  } while (0)

#define KT_EPILOGUE(kt_) do { \
    const float mb0 = im0 ? 0.f : -1e30f; \
    const float mb1 = im1 ? 0.f : -1e30f; \
    const float mb2 = im2 ? 0.f : -1e30f; \
    const float mb3 = im3 ? 0.f : -1e30f; \
    const bool isdiag = ((kt_) == qs); \
    _Pragma("unroll") \
    for (int i = 0; i < 4; ++i) { \
      _Pragma("unroll") \
      for (int rg = 0; rg < 4; ++rg) { \
        float v0 = fmaf(acc[i][0][rg], scale, mb0); \
        float v1 = fmaf(acc[i][1][rg], scale, mb1); \
        float v2 = fmaf(acc[i][2][rg], scale, mb2); \
        float v3 = fmaf(acc[i][3][rg], scale, mb3); \
        if (isdiag) { \
          const int rl = wq * 64 + i * 16 + fq * 4 + rg; \
          const int cl = wk * 64 + fr; \
          if (cl      == rl) sdg[(size_t)bb * TT + q0 + rl] = v0; \
          if (cl + 16 == rl) sdg[(size_t)bb * TT + q0 + rl] = v1; \
          if (cl + 32 == rl) sdg[(size_t)bb * TT + q0 + rl] = v2; \
          if (cl + 48 == rl) sdg[(size_t)bb * TT + q0 + rl] = v3; \
        } \
        zacc[i][rg] += __expf(v0) + __expf(v1) + __expf(v2) + __expf(v3); \
      } \
    } \
    _Pragma("unroll") \
    for (int i = 0; i < 4; ++i) \
      _Pragma("unroll") \
      for (int j = 0; j < 4; ++j) acc[i][j] = (f32x4)(0.f); \
  } while (0)

  STAGE(0, 0);
  QLOAD(avA, 0);
  __syncthreads();

  for (int p = 0; p < P; ++p) {
    const int buf = p & 1;
    const int kt = lo + p / 12, c = p % 12;
    if (c == 0) {
      const int kb = bb * TT + kt * 128 + wk * 64 + fr;
      im0 = mask[kb]; im1 = mask[kb + 16]; im2 = mask[kb + 32]; im3 = mask[kb + 48];
    }

    QLOAD(avB, 2 * c + 1);
    if (p + 1 < P) STAGE(buf ^ 1, p + 1);
    MFMA_ALL(avA, buf, 0);

    if (p + 1 < P) QLOAD(avA, 2 * (((p + 1) % 12)));
    MFMA_ALL(avB, buf, 4096);

    if (c == 11) KT_EPILOGUE(kt);

    __syncthreads();
  }
#undef STAGE
#undef QLOAD
#undef MFMA_ALL
#undef KT_EPILOGUE

  const int slot = kh * 2 + wk;
#pragma unroll
  for (int i = 0; i < 4; ++i) {
#pragma unroll
    for (int rg = 0; rg < 4; ++rg) {
      float z = zacc[i][rg];
#pragma unroll
      for (int off = 1; off < 16; off <<= 1) z += __shfl_xor(z, off);
      if (fr == 0) {
        const int row = wq * 64 + i * 16 + fq * 4 + rg;
        pzv[(size_t)slot * MM + bb * TT + q0 + row] = z;
      }
    }
  }
}

// ---------------- merge 6 partials -> wdiag (+ zero out) ----------------
__global__ void merge6(const float* __restrict__ pz, const float* __restrict__ sdg,
                       float* __restrict__ wdiag, float* __restrict__ out) {
  int i = blockIdx.x * 256 + threadIdx.x;
  if (i < BB * DD) out[i] = 0.f;
  if (i >= MM) return;
  float Z = 0.f;
#pragma unroll
  for (int s = 0; s < 6; ++s) Z += pz[(size_t)s * MM + i];
  wdiag[i] = __expf(sdg[i]) / Z;
}

// out[b,d] = sum_t X[b,t,d] * wdiag[b,t]  (f32 X fallback)
__global__ __launch_bounds__(256)
void out_gemv(const float* __restrict__ X, const float* __restrict__ wdiag,
              float* __restrict__ out) {
  __shared__ float wsm[256];
  const int b = blockIdx.z;
  const int d = blockIdx.y * 256 + threadIdx.x;
  const int tbase = blockIdx.x * 256;
  wsm[threadIdx.x] = wdiag[b * TT + tbase + threadIdx.x];
  __syncthreads();
  float acc = 0.f;
  const float* xp = X + (size_t)(b * TT + tbase) * DD + d;
#pragma unroll 4
  for (int i = 0; i < 256; ++i) acc += xp[(size_t)i * DD] * wsm[i];
  atomicAdd(&out[b * DD + d], acc);
}

// out[b,d] = sum_t Xh[b,t,d] * wdiag[b,t]  (f16 X, half the traffic)
__global__ __launch_bounds__(256)
void out_gemv_h(const f16* __restrict__ Xh, const float* __restrict__ wdiag,
                float* __restrict__ out) {
  __shared__ float wsm[256];
  const int b = blockIdx.z;
  const int d = blockIdx.y * 256 + threadIdx.x;
  const int tbase = blockIdx.x * 256;
  wsm[threadIdx.x] = wdiag[b * TT + tbase + threadIdx.x];
  __syncthreads();
  float acc = 0.f;
  const f16* xp = Xh + (size_t)(b * TT + tbase) * DD + d;
#pragma unroll 4
  for (int i = 0; i < 256; ++i) acc += (float)xp[(size_t)i * DD] * wsm[i];
  atomicAdd(&out[b * DD + d], acc);
}

extern "C" void kernel_launch(void* const* d_in, const int* in_sizes, int n_in,
                              void* d_out, int out_size, void* d_ws, size_t ws_size,
                              hipStream_t stream) {
  const float* X    = (const float*)d_in[0];
  const int*   mask = (const int*)d_in[1];
  const float* Wq_w = (const float*)d_in[2];
  const float* Wq_b = (const float*)d_in[3];
  const float* Wk_w = (const float*)d_in[4];
  const float* Wk_b = (const float*)d_in[5];
  float* out = (float*)d_out;

  const size_t n2 = (size_t)MM * DD;              // 25.17M f16 elems
  const size_t wreg = 2 * (size_t)DD * DD;
  const size_t need_full = (3 * n2 + wreg) * sizeof(f16);  // ~153.4 MB
  const bool useXh = ws_size >= need_full;

  f16* Qf  = (f16*)d_ws;                          // fragment-major Q
  f16* Kh  = Qf + n2;                             // row-major K
  f16* Xh  = useXh ? (Kh + n2) : nullptr;         // f16 copy of X (for gemv)
  f16* Wqh = useXh ? (Xh + n2) : (Kh + n2);       // f16 weights (dead after proj)
  f16* Wkh = Wqh + (size_t)DD * DD;
  float* pz    = (float*)Wqh;                     // alias after proj reads
  float* sdg   = pz + 6 * (size_t)MM;
  float* wdiag = sdg + MM;

  cvt2_f32_f16<<<576, 256, 0, stream>>>(Wq_w, Wk_w, Wqh, Wkh, DD * DD);

  proj_qk<<<dim3(512, 3, 2), 256, 0, stream>>>(X, Wqh, Wkh, Wq_b, Wk_b,
                                               Qf, Kh, Xh);

  attn15<<<768, 256, 0, stream>>>(Qf, Kh, mask, pz, sdg);

  merge6<<<128, 256, 0, stream>>>(pz, sdg, wdiag, out);

  if (useXh)
    out_gemv_h<<<dim3(16, 3, 8), 256, 0, stream>>>(Xh, wdiag, out);
  else
    out_gemv<<<dim3(16, 3, 8), 256, 0, stream>>>(X, wdiag, out);
}